// Round 13
// baseline (367.744 us; speedup 1.0000x reference)
//
#include <hip/hip_runtime.h>

constexpr int H = 1024, W = 1024, FID = 100, NF = 8;
constexpr int NPTS = 1 << 20, KSTEPS = 20;
constexpr int HW = H * W;

constexpr int NTX = 16, NTY = 32, NTILES = NTX * NTY;       // 512 tiles (64x32 px)
constexpr int TPIX = 64 * 32;                               // 2048 px/tile
constexpr int NBLK = 2048;                                  // scatter phase blocks (8/CU)
constexpr int PPB = NPTS / NBLK;                            // 512 points/block
constexpr int PPT = PPB / 256;                              // 2 points/thread
constexpr int NBLK_C = 1024;                                // count blocks (1024 pts each)
constexpr int NCPY = 4;                                     // cursor copies per tile
constexpr int HSTR = NBLK * NCPY;                           // hist stride per tile = 8192
constexpr int CHUNK = 16384;                                // records per accum WG
constexpr int TH    = 16384;                                // dense-tile threshold (= CHUNK)
constexpr int MAXREC = NPTS * KSTEPS;                       // 20,971,520
constexpr int K4_GRID = MAXREC / CHUNK;                     // 1280
constexpr int K4_BS  = 512;                                 // accum block size
constexpr int MAXVIS = K4_GRID + NTILES;                    // 1792 slot cap
constexpr unsigned INV = 0xFFFFFFFFu;
constexpr float QSCALE = 16384.0f;                          // _c fixed-point scale
constexpr float QINV   = 1.0f / 16384.0f;
constexpr float FXS  = 131072.0f;                           // 2^17 channel fixed-point
constexpr float FXSI = 1.0f / 131072.0f;
// overflow safety: (TH-1) * 2^17 < 2^32 (u32 halves, unsigned) -- OK.
// copy(n) = ((n>>2)+(n&3))&3 -- pure function of point index, so count's
// per-(tile,blk,copy) histogram exactly sizes scatter's per-copy segments.

// decode packed record -> 4 channel values + local pixel
__device__ __forceinline__ void decode_rec(unsigned r, const float4* sPal,
                                           int& pix, float& v0, float& v1,
                                           float& v2, float& v3) {
    pix = (int)(r & 2047u);
    const float _c = (float)(r >> 11) * QINV;       // = c * 100, quantized
    const float cf = floorf(_c);
    const float tt = _c - cf;
    const int cfi = (int)fminf(fmaxf(cf, 0.f), (float)FID);
    const int cci = (int)fminf(fmaxf(ceilf(_c), 0.f), (float)FID);
    const float4 pc = sPal[cci];
    const float4 pf = sPal[cfi];
    const float omt = 1.f - tt;
    v0 = tt * pc.x + omt * pf.x;
    v1 = tt * pc.y + omt * pf.y;
    v2 = tt * pc.z + omt * pf.z;
    v3 = tt * pc.w + omt * pf.w;
}

__device__ __forceinline__ unsigned long long pack2(float a, float b) {
    const unsigned ua = __float2uint_rn(a * FXS);
    const unsigned ub = __float2uint_rn(b * FXS);
    return (unsigned long long)ua | ((unsigned long long)ub << 32);
}

// ---------- K1: count hits per (tile, scatter-block, copy); pack choices ----------
// 4 points/thread in lockstep over k (int4 choices load, 4x ILP). Histogram
// split 4 ways by copy=(t+j)&3: intra-wave same-address atomic depth 64 -> 16.
__global__ __launch_bounds__(256)
void count_kernel(const float* __restrict__ points,
                  const int* __restrict__ choices,
                  const float* __restrict__ A,
                  const float* __restrict__ b,
                  const float* __restrict__ minv,
                  const float* __restrict__ rangev,
                  const int* __restrict__ skipp,
                  unsigned* __restrict__ hist,
                  unsigned long long* __restrict__ packed)
{
    __shared__ float sA[NF * 4], sB[NF * 2];
    __shared__ unsigned shist[4][NCPY][NTILES];   // 32 KB: [wave][copy][tile]
    const int t = threadIdx.x;
    if (t < NF * 4) sA[t] = A[t];
    if (t < NF * 2) sB[t] = b[t];
    for (int i = t; i < 4 * NCPY * NTILES; i += 256) ((unsigned*)shist)[i] = 0u;
    __syncthreads();

    const int blk = blockIdx.x;
    const int base = blk * 1024;
    const int n0 = base + 4 * t;
    const float mx = minv[0], my = minv[1], rx = rangev[0], ry = rangev[1];
    const int skip = skipp[0];
    const int wv = t >> 6;

    const float4 f0 = *(const float4*)&points[3 * n0 + 0];
    const float4 f1 = *(const float4*)&points[3 * n0 + 4];
    const float4 f2 = *(const float4*)&points[3 * n0 + 8];
    float px_[4] = { f0.x, f0.w, f1.z, f2.y };
    float py_[4] = { f0.y, f1.x, f1.w, f2.z };

    unsigned long long pk_[4] = { 0ull, 0ull, 0ull, 0ull };
    unsigned ctile_[4] = { INV, INV, INV, INV };
    unsigned ccnt_[4]  = { 0u, 0u, 0u, 0u };

#pragma unroll
    for (int k = 0; k < KSTEPS; ++k) {
        const int4 cv = *(const int4*)&choices[k * NPTS + n0];
        const int idxs[4] = { cv.x & 7, cv.y & 7, cv.z & 7, cv.w & 7 };
#pragma unroll
        for (int j = 0; j < 4; ++j) {
            const int idx = idxs[j];
            pk_[j] |= (unsigned long long)idx << (3 * k);
            const float nx = sA[idx*4+0]*px_[j] + sA[idx*4+1]*py_[j] + sB[idx*2+0];
            const float ny = sA[idx*4+2]*px_[j] + sA[idx*4+3]*py_[j] + sB[idx*2+1];
            px_[j] = nx; py_[j] = ny;
            const int xb = (int)((nx - mx) * rx);
            const int yb = (int)((ny - my) * ry);
            if (k >= skip && (unsigned)xb < (unsigned)W && (unsigned)yb < (unsigned)H) {
                const unsigned tile = (unsigned)(((xb >> 6) << 5) | (yb >> 5));
                if (tile == ctile_[j]) { ++ccnt_[j]; }
                else {
                    if (ctile_[j] != INV)
                        atomicAdd(&shist[wv][(t + j) & 3][ctile_[j]], ccnt_[j]);
                    ctile_[j] = tile; ccnt_[j] = 1;
                }
            }
        }
    }
#pragma unroll
    for (int j = 0; j < 4; ++j) {
        if (ctile_[j] != INV) atomicAdd(&shist[wv][(t + j) & 3][ctile_[j]], ccnt_[j]);
        packed[n0 + j] = pk_[j];
    }
    __syncthreads();
    // waves 0-1 = scatter blk 2*blk (points base..base+511); waves 2-3 = 2*blk+1
    for (int tt = t; tt < NTILES; tt += 256) {
#pragma unroll
        for (int c = 0; c < NCPY; ++c) {
            hist[(size_t)tt * HSTR + (2 * blk)     * NCPY + c] = shist[0][c][tt] + shist[1][c][tt];
            hist[(size_t)tt * HSTR + (2 * blk + 1) * NCPY + c] = shist[2][c][tt] + shist[3][c][tt];
        }
    }
}

// ---------- K2a: per-tile exclusive scan over NBLK*NCPY entries (8/thread) ----------
__global__ __launch_bounds__(1024)
void scan1_kernel(unsigned* __restrict__ hist, unsigned* __restrict__ sums)
{
    __shared__ unsigned buf[2][1024];
    const int t = threadIdx.x;
    const size_t base = (size_t)blockIdx.x * HSTR;
    unsigned v[8];
    unsigned s = 0;
#pragma unroll
    for (int j = 0; j < 8; ++j) { v[j] = hist[base + 8 * t + j]; s += v[j]; }
    int src = 0;
    buf[0][t] = s; __syncthreads();
    for (int off = 1; off < 1024; off <<= 1) {
        unsigned val = buf[src][t];
        if (t >= off) val += buf[src][t - off];
        buf[1 - src][t] = val; src ^= 1; __syncthreads();
    }
    const unsigned incl = buf[src][t];
    unsigned ex = incl - s;
#pragma unroll
    for (int j = 0; j < 8; ++j) { hist[base + 8 * t + j] = ex; ex += v[j]; }
    if (t == 1023) sums[blockIdx.x] = incl;
}

// ---------- K2b: 3 scans — global starts, dense starts, visit offsets ----------
__global__ __launch_bounds__(512)
void scan2v_kernel(unsigned* __restrict__ sums,
                   unsigned* __restrict__ dstart,
                   unsigned* __restrict__ vstart)
{
    __shared__ unsigned buf[2][512];
    const int t = threadIdx.x;
    const unsigned len = sums[t];

    int src = 0;
    buf[0][t] = len; __syncthreads();
    for (int off = 1; off < 512; off <<= 1) {
        unsigned val = buf[src][t];
        if (t >= off) val += buf[src][t - off];
        buf[1 - src][t] = val; src ^= 1; __syncthreads();
    }
    unsigned incl = buf[src][t];
    sums[t] = incl - len;
    if (t == 511) sums[512] = incl;

    const unsigned dlen = (len >= (unsigned)TH) ? len : 0u;
    __syncthreads();
    buf[0][t] = dlen; src = 0; __syncthreads();
    for (int off = 1; off < 512; off <<= 1) {
        unsigned val = buf[src][t];
        if (t >= off) val += buf[src][t - off];
        buf[1 - src][t] = val; src ^= 1; __syncthreads();
    }
    unsigned dincl = buf[src][t];
    const unsigned dexcl = dincl - dlen;
    dstart[t] = dexcl;
    if (t == 511) dstart[512] = dincl;

    unsigned c = 0;
    if (dlen) c = (dexcl + dlen - 1) / CHUNK - dexcl / CHUNK + 1;
    __syncthreads();
    buf[0][t] = c; src = 0; __syncthreads();
    for (int off = 1; off < 512; off <<= 1) {
        unsigned val = buf[src][t];
        if (t >= off) val += buf[src][t - off];
        buf[1 - src][t] = val; src ^= 1; __syncthreads();
    }
    unsigned vincl = buf[src][t];
    vstart[t] = vincl - c;
    if (t == 511) vstart[512] = vincl;
}

// ---------- K3: barrier-free scatter, 4-way copy-split cursors ----------
// copy = ((t>>2)+(t&3))&3 (== ((n>>2)+(n&3))&3 for this thread's points):
// 16 lanes per copy per wave -> same-address atomic depth ~4x lower.
__global__ __launch_bounds__(256)
void scatter_kernel(const float* __restrict__ points,
                    const unsigned long long* __restrict__ packed,
                    const float* __restrict__ A,
                    const float* __restrict__ b,
                    const float* __restrict__ fc,
                    const float* __restrict__ minv,
                    const float* __restrict__ rangev,
                    const int* __restrict__ skipp,
                    const unsigned* __restrict__ scanb,   // = hist after scan
                    const unsigned* __restrict__ sums,
                    unsigned* __restrict__ records)
{
    __shared__ float sA[NF * 4], sB[NF * 2], sFC[NF];
    __shared__ unsigned sCur[NCPY * NTILES];   // 8 KB: [copy][tile]

    const int t = threadIdx.x;
    const int blk = blockIdx.x;
    if (t < NF * 4) sA[t] = A[t];
    if (t < NF * 2) sB[t] = b[t];
    if (t < NF)     sFC[t] = fc[t];
    for (int i = t; i < NCPY * NTILES; i += 256) {
        const int tile = i & (NTILES - 1);
        const int c = i >> 9;                  // NTILES = 512
        sCur[c * NTILES + tile] =
            scanb[(size_t)tile * HSTR + blk * NCPY + c] + sums[tile];
    }
    __syncthreads();

    const int base = blk * PPB;
    const float mx = minv[0], my = minv[1], rx = rangev[0], ry = rangev[1];
    const int skip = skipp[0];
    const int cpy = ((t >> 2) + (t & 3)) & 3;  // constant per thread
    unsigned* const myCur = &sCur[cpy * NTILES];

    for (int p = 0; p < PPT; ++p) {
        const int n = base + p * 256 + t;
        float x = points[3*n], y = points[3*n+1], c = points[3*n+2];
        const unsigned long long pk = packed[n];

#pragma unroll
        for (int k = 0; k < KSTEPS; ++k) {
            const int idx = (int)((pk >> (3 * k)) & 7ull);
            const float nx = sA[idx*4+0]*x + sA[idx*4+1]*y + sB[idx*2+0];
            const float ny = sA[idx*4+2]*x + sA[idx*4+3]*y + sB[idx*2+1];
            c = 0.5f * (c + sFC[idx]);
            x = nx; y = ny;
            const int xb = (int)((nx - mx) * rx);
            const int yb = (int)((ny - my) * ry);
            if (k >= skip && (unsigned)xb < (unsigned)W && (unsigned)yb < (unsigned)H) {
                const unsigned tile = (unsigned)(((xb >> 6) << 5) | (yb >> 5));
                const unsigned q = (unsigned)__float2int_rn(c * (100.0f * QSCALE));
                const unsigned rec = (q << 11) | (unsigned)(((xb & 63) << 5) | (yb & 31));
                const unsigned pos = atomicAdd(&myCur[tile], 1u);
                records[pos] = rec;
            }
        }
    }
}

// ---------- K4: dense-tile LDS accumulate, u64 packed fixed-point atomics ----------
__global__ __launch_bounds__(K4_BS)
void accum_slot_kernel(const unsigned* __restrict__ records,
                       const unsigned* __restrict__ sums,
                       const unsigned* __restrict__ dstart,
                       const unsigned* __restrict__ vstart,
                       const float* __restrict__ palette,
                       float* __restrict__ slots)
{
    __shared__ unsigned long long img01[TPIX];   // ch0|ch1 packed, 16 KB
    __shared__ unsigned long long img23[TPIX];   // ch2|ch3 packed, 16 KB
    __shared__ float4 sPal[FID + 1];
    __shared__ unsigned tstart[NTILES + 1];
    __shared__ unsigned dst[NTILES + 1];
    __shared__ unsigned vst[NTILES];
    const int t = threadIdx.x;
    for (int i = t; i < NTILES + 1; i += K4_BS) { tstart[i] = sums[i]; dst[i] = dstart[i]; }
    for (int i = t; i < NTILES; i += K4_BS) vst[i] = vstart[i];
    for (int i = t; i < (FID + 1) * 4; i += K4_BS) ((float*)sPal)[i] = palette[i];
    __syncthreads();

    const unsigned dtotal = dst[NTILES];
    const unsigned r0 = (unsigned)blockIdx.x * CHUNK;
    if (r0 >= dtotal) return;
    const unsigned r1 = min(r0 + (unsigned)CHUNK, dtotal);

    int lo = 0, hi = NTILES;
    while (lo < hi) {
        const int mid = (lo + hi + 1) >> 1;
        if (dst[mid] <= r0) lo = mid; else hi = mid - 1;
    }

    for (int tile = lo; tile < NTILES && dst[tile] < r1; ++tile) {
        const unsigned sd = max(dst[tile], r0);
        const unsigned ed = min(dst[tile + 1], r1);
        if (sd >= ed) continue;
        const unsigned gs = tstart[tile] + (sd - dst[tile]);
        const unsigned ge = gs + (ed - sd);

        for (int i = t; i < TPIX; i += K4_BS) { img01[i] = 0ull; img23[i] = 0ull; }
        __syncthreads();

        // 2 u64 atomics per record. Fixed-point 2^17: CHUNK x 2^17 = 2^31 < 2^32 (u32).
        const unsigned abase = gs & ~3u;
        for (unsigned i = abase + 4u * (unsigned)t; i < ge; i += 4u * K4_BS) {
            const uint4 r4 = *(const uint4*)&records[i];
            const unsigned rr[4] = { r4.x, r4.y, r4.z, r4.w };
#pragma unroll
            for (int j = 0; j < 4; ++j) {
                const unsigned ri = i + (unsigned)j;
                if (ri >= gs && ri < ge) {
                    int pix; float v0, v1, v2, v3;
                    decode_rec(rr[j], sPal, pix, v0, v1, v2, v3);
                    atomicAdd(&img01[pix], pack2(v0, v1));
                    atomicAdd(&img23[pix], pack2(v2, v3));
                }
            }
        }
        __syncthreads();

        const unsigned slot = vst[tile] + ((unsigned)blockIdx.x - dst[tile] / CHUNK);
        float* sp = slots + (size_t)slot * (4 * TPIX);
        for (int i2 = t; i2 < TPIX; i2 += K4_BS) {
            const unsigned long long a = img01[i2];
            const unsigned long long bb = img23[i2];
            sp[0 * TPIX + i2] = (float)(unsigned)(a  & 0xFFFFFFFFu) * FXSI;
            sp[1 * TPIX + i2] = (float)(unsigned)(a  >> 32)         * FXSI;
            sp[2 * TPIX + i2] = (float)(unsigned)(bb & 0xFFFFFFFFu) * FXSI;
            sp[3 * TPIX + i2] = (float)(unsigned)(bb >> 32)         * FXSI;
        }
        __syncthreads();
    }
}

// ---------- K5: one 1024-thread block per tile: slots sum + single-pass sparse ----------
__global__ __launch_bounds__(1024)
void reduce_kernel(const float* __restrict__ slots,
                   const unsigned* __restrict__ vstart,
                   const unsigned* __restrict__ sums,
                   const unsigned* __restrict__ records,
                   const float* __restrict__ palette,
                   const float* __restrict__ raw0,
                   float* __restrict__ out)
{
    __shared__ unsigned long long l01[TPIX];     // 16 KB
    __shared__ unsigned long long l23[TPIX];     // 16 KB
    __shared__ float4 sPal[FID + 1];
    const int T = blockIdx.x;               // tile
    const int t = threadIdx.x;
    for (int i = t; i < (FID + 1) * 4; i += 1024) ((float*)sPal)[i] = palette[i];

    const unsigned v0 = vstart[T], v1 = vstart[T + 1];
    const unsigned s = sums[T], e = sums[T + 1];
    const bool sparse = (v0 == v1) && (e > s);
    if (sparse) for (int i = t; i < TPIX; i += 1024) { l01[i] = 0ull; l23[i] = 0ull; }
    __syncthreads();

    float4 acc0 = {0.f,0.f,0.f,0.f}, acc1 = {0.f,0.f,0.f,0.f};
    for (unsigned v = v0; v < v1; ++v) {
        const float4* sp = (const float4*)(slots + (size_t)v * (4 * TPIX));
        const float4 a = sp[t];
        const float4 bq = sp[t + 1024];
        acc0.x += a.x;  acc0.y += a.y;  acc0.z += a.z;  acc0.w += a.w;
        acc1.x += bq.x; acc1.y += bq.y; acc1.z += bq.z; acc1.w += bq.w;
    }

    if (sparse) {
        // < TH records: 2^17 fixed-point safe ((TH-1) * 2^17 < 2^32 unsigned)
        for (unsigned i = s + t; i < e; i += 1024) {
            int pix; float w0, w1, w2, w3;
            decode_rec(records[i], sPal, pix, w0, w1, w2, w3);
            atomicAdd(&l01[pix], pack2(w0, w1));
            atomicAdd(&l23[pix], pack2(w2, w3));
        }
    }
    __syncthreads();

    const int tx = T >> 5, ty = T & 31;
#pragma unroll
    for (int half = 0; half < 2; ++half) {
        const int f  = t + half * 1024;     // float4 index in [0, 2048)
        const int ch = f >> 9;              // TPIX/4 = 512 float4s per channel
        const int q  = f & 511;
        const int p0 = q * 4;               // first of 4 consecutive local pixels
        float4 acc = half ? acc1 : acc0;
        if (sparse) {
#pragma unroll
            for (int j = 0; j < 4; ++j) {
                const int p = p0 + j;
                float vadd;
                if (ch == 0)      vadd = (float)(unsigned)(l01[p] & 0xFFFFFFFFu) * FXSI;
                else if (ch == 1) vadd = (float)(unsigned)(l01[p] >> 32) * FXSI;
                else if (ch == 2) vadd = (float)(unsigned)(l23[p] & 0xFFFFFFFFu) * FXSI;
                else              vadd = (float)(unsigned)(l23[p] >> 32) * FXSI;
                if (j == 0) acc.x += vadd;
                else if (j == 1) acc.y += vadd;
                else if (j == 2) acc.z += vadd;
                else acc.w += vadd;
            }
        }
        const int px = p0 >> 5, py = p0 & 31;
        const size_t o = (size_t)ch * HW + (size_t)(tx * 64 + px) * W + (ty * 32 + py);
        const float4 r = *(const float4*)(raw0 + o);
        acc.x += r.x; acc.y += r.y; acc.z += r.z; acc.w += r.w;
        *(float4*)(out + o) = acc;
    }
}

// ---------- Fallback: direct planar atomics ----------
__global__ __launch_bounds__(256)
void flame_kernel_planar(const float* __restrict__ points,
                         const int* __restrict__ choices,
                         const float* __restrict__ A,
                         const float* __restrict__ b,
                         const float* __restrict__ fc,
                         const float* __restrict__ palette,
                         const float* __restrict__ min_vec,
                         const float* __restrict__ range_vec,
                         const int* __restrict__ skipp,
                         float* __restrict__ out)
{
    __shared__ float sA[NF * 4];
    __shared__ float sB[NF * 2];
    __shared__ float sFC[NF];
    __shared__ float4 sPal[FID + 1];
    const int t = threadIdx.x;
    if (t < NF * 4) sA[t] = A[t];
    if (t < NF * 2) sB[t] = b[t];
    if (t < NF)     sFC[t] = fc[t];
    for (int i = t; i < (FID + 1) * 4; i += 256) ((float*)sPal)[i] = palette[i];
    __syncthreads();

    const int n = blockIdx.x * 256 + t;
    float x = points[3 * n], y = points[3 * n + 1], c = points[3 * n + 2];
    const float mx = min_vec[0], my = min_vec[1];
    const float rx = range_vec[0], ry = range_vec[1];
    const int skip = skipp[0];

    for (int k = 0; k < KSTEPS; ++k) {
        const int idx = choices[k * NPTS + n];
        const float nx = sA[idx*4+0]*x + sA[idx*4+1]*y + sB[idx*2+0];
        const float ny = sA[idx*4+2]*x + sA[idx*4+3]*y + sB[idx*2+1];
        c = 0.5f * (c + sFC[idx]);
        x = nx; y = ny;
        const float _c = c * (float)FID;
        const float cf = floorf(_c);
        const float tt = _c - cf;
        const int cfi = (int)fminf(fmaxf(cf, 0.f), (float)FID);
        const int cci = (int)fminf(fmaxf(ceilf(_c), 0.f), (float)FID);
        const float4 pc = sPal[cci];
        const float4 pf = sPal[cfi];
        const int xb = (int)((nx - mx) * rx);
        const int yb = (int)((ny - my) * ry);
        if (k >= skip && (unsigned)xb < (unsigned)W && (unsigned)yb < (unsigned)H) {
            const int p = xb * W + yb;
            const float omt = 1.f - tt;
            atomicAdd(out + p + 0 * HW, tt * pc.x + omt * pf.x);
            atomicAdd(out + p + 1 * HW, tt * pc.y + omt * pf.y);
            atomicAdd(out + p + 2 * HW, tt * pc.z + omt * pf.z);
            atomicAdd(out + p + 3 * HW, tt * pc.w + omt * pf.w);
        }
    }
}

extern "C" void kernel_launch(void* const* d_in, const int* in_sizes, int n_in,
                              void* d_out, int out_size, void* d_ws, size_t ws_size,
                              hipStream_t stream) {
    const float* points    = (const float*)d_in[0];
    const int*   choices   = (const int*)d_in[1];
    const float* A         = (const float*)d_in[2];
    const float* b         = (const float*)d_in[3];
    const float* fc        = (const float*)d_in[4];
    const float* palette   = (const float*)d_in[5];
    const float* min_vec   = (const float*)d_in[6];
    const float* range_vec = (const float*)d_in[7];
    const float* raw0      = (const float*)d_in[8];
    const int*   skipp     = (const int*)d_in[9];
    float* out = (float*)d_out;
    const size_t img_bytes = (size_t)4 * HW * sizeof(float);   // 16 MB

    // Layout: records | sums | dstart | vstart | slots-region.
    // packed (8 MB) and hist (16 MB) live INSIDE the slots region: both are
    // dead before K4 writes slots (stream-ordered), so no extra footprint.
    const size_t rec_off  = 0;
    const size_t rec_cap  = (size_t)MAXREC * 4;                 // 84 MB (u32 records)
    const size_t sums_off = rec_off + rec_cap;
    const size_t dst_off  = sums_off + 4096;
    const size_t vst_off  = dst_off + 4096;
    const size_t slot_off = vst_off + 4096;
    const size_t slot_cap = (size_t)MAXVIS * (4 * TPIX) * sizeof(float);  // 58.7 MB
    const size_t pk_off   = slot_off;                           // 8 MB
    const size_t hist_off = slot_off + (size_t)NPTS * 8;        // 16 MiB
    const size_t need1    = slot_off + slot_cap;                // ~143 MB

    unsigned* sums = (unsigned*)((char*)d_ws + sums_off);
    unsigned* recs = (unsigned*)((char*)d_ws + rec_off);

    if (ws_size >= need1) {
        unsigned* hist   = (unsigned*)((char*)d_ws + hist_off);
        unsigned* dstart = (unsigned*)((char*)d_ws + dst_off);
        unsigned* vstart = (unsigned*)((char*)d_ws + vst_off);
        float*    slots  = (float*)((char*)d_ws + slot_off);
        unsigned long long* packed = (unsigned long long*)((char*)d_ws + pk_off);

        count_kernel<<<NBLK_C, 256, 0, stream>>>(
            points, choices, A, b, min_vec, range_vec, skipp, hist, packed);
        scan1_kernel<<<NTILES, 1024, 0, stream>>>(hist, sums);
        scan2v_kernel<<<1, 512, 0, stream>>>(sums, dstart, vstart);
        scatter_kernel<<<NBLK, 256, 0, stream>>>(
            points, packed, A, b, fc, min_vec, range_vec, skipp, hist, sums, recs);
        accum_slot_kernel<<<K4_GRID, K4_BS, 0, stream>>>(
            recs, sums, dstart, vstart, palette, slots);
        reduce_kernel<<<NTILES, 1024, 0, stream>>>(
            slots, vstart, sums, recs, palette, raw0, out);
    } else {
        hipMemcpyAsync(out, raw0, img_bytes, hipMemcpyDeviceToDevice, stream);
        flame_kernel_planar<<<NPTS / 256, 256, 0, stream>>>(
            points, choices, A, b, fc, palette, min_vec, range_vec, skipp, out);
    }
}

// Round 14
// 306.728 us; speedup vs baseline: 1.1989x; 1.1989x over previous
//
#include <hip/hip_runtime.h>

constexpr int H = 1024, W = 1024, FID = 100, NF = 8;
constexpr int NPTS = 1 << 20, KSTEPS = 20;
constexpr int HW = H * W;

constexpr int NTX = 16, NTY = 32, NTILES = NTX * NTY;       // 512 tiles (64x32 px)
constexpr int TPIX = 64 * 32;                               // 2048 px/tile
constexpr int NBLK = 2048;                                  // scatter phase blocks (8/CU)
constexpr int PPB = NPTS / NBLK;                            // 512 points/block
constexpr int PPT = PPB / 256;                              // 2 points/thread
constexpr int NBLK_C = 1024;                                // count blocks (1024 pts each)
constexpr int NCPY = 4;                                     // LDS histogram copies (count only)
constexpr int CHUNK = 16384;                                // records per accum WG
constexpr int TH    = 16384;                                // dense-tile threshold (= CHUNK)
constexpr int MAXREC = NPTS * KSTEPS;                       // 20,971,520
constexpr int K4_GRID = MAXREC / CHUNK;                     // 1280
constexpr int K4_BS  = 512;                                 // accum block size
constexpr int MAXVIS = K4_GRID + NTILES;                    // 1792 slot cap
constexpr unsigned INV = 0xFFFFFFFFu;
constexpr float QSCALE = 16384.0f;                          // _c fixed-point scale
constexpr float QINV   = 1.0f / 16384.0f;
constexpr float FXS  = 131072.0f;                           // 2^17 channel fixed-point
constexpr float FXSI = 1.0f / 131072.0f;
// overflow safety: (TH-1) * 2^17 < 2^32 (u32 halves, unsigned) -- OK.

// decode packed record -> 4 channel values + local pixel
__device__ __forceinline__ void decode_rec(unsigned r, const float4* sPal,
                                           int& pix, float& v0, float& v1,
                                           float& v2, float& v3) {
    pix = (int)(r & 2047u);
    const float _c = (float)(r >> 11) * QINV;       // = c * 100, quantized
    const float cf = floorf(_c);
    const float tt = _c - cf;
    const int cfi = (int)fminf(fmaxf(cf, 0.f), (float)FID);
    const int cci = (int)fminf(fmaxf(ceilf(_c), 0.f), (float)FID);
    const float4 pc = sPal[cci];
    const float4 pf = sPal[cfi];
    const float omt = 1.f - tt;
    v0 = tt * pc.x + omt * pf.x;
    v1 = tt * pc.y + omt * pf.y;
    v2 = tt * pc.z + omt * pf.z;
    v3 = tt * pc.w + omt * pf.w;
}

__device__ __forceinline__ unsigned long long pack2(float a, float b) {
    const unsigned ua = __float2uint_rn(a * FXS);
    const unsigned ub = __float2uint_rn(b * FXS);
    return (unsigned long long)ua | ((unsigned long long)ub << 32);
}

// ---------- K1: count hits per (tile, scatter-block); pack choices -> u64 ----------
// 4 points/thread in lockstep over k (int4 choices load, 4x ILP). LDS-internal
// 4-way histogram copy-split (copy=(t+j)&3): intra-wave same-address atomic
// depth 64 -> 16. Copies summed at write-out -> global hist layout unchanged
// (avoids R13's strided-init FETCH explosion).
__global__ __launch_bounds__(256)
void count_kernel(const float* __restrict__ points,
                  const int* __restrict__ choices,
                  const float* __restrict__ A,
                  const float* __restrict__ b,
                  const float* __restrict__ minv,
                  const float* __restrict__ rangev,
                  const int* __restrict__ skipp,
                  unsigned* __restrict__ hist,
                  unsigned long long* __restrict__ packed)
{
    __shared__ float sA[NF * 4], sB[NF * 2];
    __shared__ unsigned shist[4][NCPY][NTILES];   // 32 KB: [wave][copy][tile]
    const int t = threadIdx.x;
    if (t < NF * 4) sA[t] = A[t];
    if (t < NF * 2) sB[t] = b[t];
    for (int i = t; i < 4 * NCPY * NTILES; i += 256) ((unsigned*)shist)[i] = 0u;
    __syncthreads();

    const int blk = blockIdx.x;
    const int base = blk * 1024;
    const int n0 = base + 4 * t;
    const float mx = minv[0], my = minv[1], rx = rangev[0], ry = rangev[1];
    const int skip = skipp[0];
    const int wv = t >> 6;

    // load 4 points' x,y via three float4s (12 consecutive floats)
    const float4 f0 = *(const float4*)&points[3 * n0 + 0];
    const float4 f1 = *(const float4*)&points[3 * n0 + 4];
    const float4 f2 = *(const float4*)&points[3 * n0 + 8];
    float px_[4] = { f0.x, f0.w, f1.z, f2.y };
    float py_[4] = { f0.y, f1.x, f1.w, f2.z };

    unsigned long long pk_[4] = { 0ull, 0ull, 0ull, 0ull };
    unsigned ctile_[4] = { INV, INV, INV, INV };
    unsigned ccnt_[4]  = { 0u, 0u, 0u, 0u };

#pragma unroll
    for (int k = 0; k < KSTEPS; ++k) {
        const int4 cv = *(const int4*)&choices[k * NPTS + n0];
        const int idxs[4] = { cv.x & 7, cv.y & 7, cv.z & 7, cv.w & 7 };
#pragma unroll
        for (int j = 0; j < 4; ++j) {
            const int idx = idxs[j];
            pk_[j] |= (unsigned long long)idx << (3 * k);
            const float nx = sA[idx*4+0]*px_[j] + sA[idx*4+1]*py_[j] + sB[idx*2+0];
            const float ny = sA[idx*4+2]*px_[j] + sA[idx*4+3]*py_[j] + sB[idx*2+1];
            px_[j] = nx; py_[j] = ny;
            const int xb = (int)((nx - mx) * rx);
            const int yb = (int)((ny - my) * ry);
            if (k >= skip && (unsigned)xb < (unsigned)W && (unsigned)yb < (unsigned)H) {
                const unsigned tile = (unsigned)(((xb >> 6) << 5) | (yb >> 5));
                if (tile == ctile_[j]) { ++ccnt_[j]; }
                else {
                    if (ctile_[j] != INV)
                        atomicAdd(&shist[wv][(t + j) & 3][ctile_[j]], ccnt_[j]);
                    ctile_[j] = tile; ccnt_[j] = 1;
                }
            }
        }
    }
#pragma unroll
    for (int j = 0; j < 4; ++j) {
        if (ctile_[j] != INV) atomicAdd(&shist[wv][(t + j) & 3][ctile_[j]], ccnt_[j]);
        packed[n0 + j] = pk_[j];
    }
    __syncthreads();
    // waves 0-1 = scatter blk 2*blk (points base..base+511); waves 2-3 = 2*blk+1
    for (int tt = t; tt < NTILES; tt += 256) {
        unsigned h0 = 0u, h1 = 0u;
#pragma unroll
        for (int c = 0; c < NCPY; ++c) {
            h0 += shist[0][c][tt] + shist[1][c][tt];
            h1 += shist[2][c][tt] + shist[3][c][tt];
        }
        hist[tt * NBLK + 2 * blk]     = h0;
        hist[tt * NBLK + 2 * blk + 1] = h1;
    }
}

// ---------- K2a: per-tile exclusive scan over NBLK entries (2 per thread) ----------
__global__ __launch_bounds__(1024)
void scan1_kernel(unsigned* __restrict__ hist, unsigned* __restrict__ sums)
{
    __shared__ unsigned buf[2][1024];
    const int t = threadIdx.x;
    const int base = blockIdx.x * NBLK;
    const unsigned v0 = hist[base + 2 * t];
    const unsigned v1 = hist[base + 2 * t + 1];
    int src = 0;
    buf[0][t] = v0 + v1; __syncthreads();
    for (int off = 1; off < 1024; off <<= 1) {
        unsigned val = buf[src][t];
        if (t >= off) val += buf[src][t - off];
        buf[1 - src][t] = val; src ^= 1; __syncthreads();
    }
    const unsigned incl = buf[src][t];
    const unsigned ex = incl - (v0 + v1);
    hist[base + 2 * t]     = ex;
    hist[base + 2 * t + 1] = ex + v0;
    if (t == 1023) sums[blockIdx.x] = incl;
}

// ---------- K2b: 3 scans — global starts, dense starts, visit offsets ----------
__global__ __launch_bounds__(512)
void scan2v_kernel(unsigned* __restrict__ sums,
                   unsigned* __restrict__ dstart,
                   unsigned* __restrict__ vstart)
{
    __shared__ unsigned buf[2][512];
    const int t = threadIdx.x;
    const unsigned len = sums[t];

    int src = 0;
    buf[0][t] = len; __syncthreads();
    for (int off = 1; off < 512; off <<= 1) {
        unsigned val = buf[src][t];
        if (t >= off) val += buf[src][t - off];
        buf[1 - src][t] = val; src ^= 1; __syncthreads();
    }
    unsigned incl = buf[src][t];
    sums[t] = incl - len;
    if (t == 511) sums[512] = incl;

    const unsigned dlen = (len >= (unsigned)TH) ? len : 0u;
    __syncthreads();
    buf[0][t] = dlen; src = 0; __syncthreads();
    for (int off = 1; off < 512; off <<= 1) {
        unsigned val = buf[src][t];
        if (t >= off) val += buf[src][t - off];
        buf[1 - src][t] = val; src ^= 1; __syncthreads();
    }
    unsigned dincl = buf[src][t];
    const unsigned dexcl = dincl - dlen;
    dstart[t] = dexcl;
    if (t == 511) dstart[512] = dincl;

    unsigned c = 0;
    if (dlen) c = (dexcl + dlen - 1) / CHUNK - dexcl / CHUNK + 1;
    __syncthreads();
    buf[0][t] = c; src = 0; __syncthreads();
    for (int off = 1; off < 512; off <<= 1) {
        unsigned val = buf[src][t];
        if (t >= off) val += buf[src][t - off];
        buf[1 - src][t] = val; src ^= 1; __syncthreads();
    }
    unsigned vincl = buf[src][t];
    vstart[t] = vincl - c;
    if (t == 511) vstart[512] = vincl;
}

// ---------- K3: barrier-free scatter (R4/R10 form -- proven 86-88 us floor) ----------
// 1 LDS cursor atomic + 1 immediate store per record, lane-synchronized k-loop.
// Floor invariant to occupancy (18-66%), ILP batching, atomic merging, store
// grouping, and global copy-splitting (R5-R8, R13 all slower).
__global__ __launch_bounds__(256)
void scatter_kernel(const float* __restrict__ points,
                    const unsigned long long* __restrict__ packed,
                    const float* __restrict__ A,
                    const float* __restrict__ b,
                    const float* __restrict__ fc,
                    const float* __restrict__ minv,
                    const float* __restrict__ rangev,
                    const int* __restrict__ skipp,
                    const unsigned* __restrict__ scanb,   // = hist after scan
                    const unsigned* __restrict__ sums,
                    unsigned* __restrict__ records)
{
    __shared__ float sA[NF * 4], sB[NF * 2], sFC[NF];
    __shared__ unsigned sCur[NTILES];      // running global cursor per tile (this block)

    const int t = threadIdx.x;
    const int blk = blockIdx.x;
    if (t < NF * 4) sA[t] = A[t];
    if (t < NF * 2) sB[t] = b[t];
    if (t < NF)     sFC[t] = fc[t];
    for (int tt = t; tt < NTILES; tt += 256)
        sCur[tt] = scanb[tt * NBLK + blk] + sums[tt];
    __syncthreads();

    const int base = blk * PPB;
    const float mx = minv[0], my = minv[1], rx = rangev[0], ry = rangev[1];
    const int skip = skipp[0];

    for (int p = 0; p < PPT; ++p) {
        const int n = base + p * 256 + t;
        float x = points[3*n], y = points[3*n+1], c = points[3*n+2];
        const unsigned long long pk = packed[n];

#pragma unroll
        for (int k = 0; k < KSTEPS; ++k) {
            const int idx = (int)((pk >> (3 * k)) & 7ull);
            const float nx = sA[idx*4+0]*x + sA[idx*4+1]*y + sB[idx*2+0];
            const float ny = sA[idx*4+2]*x + sA[idx*4+3]*y + sB[idx*2+1];
            c = 0.5f * (c + sFC[idx]);
            x = nx; y = ny;
            const int xb = (int)((nx - mx) * rx);
            const int yb = (int)((ny - my) * ry);
            if (k >= skip && (unsigned)xb < (unsigned)W && (unsigned)yb < (unsigned)H) {
                const unsigned tile = (unsigned)(((xb >> 6) << 5) | (yb >> 5));
                const unsigned q = (unsigned)__float2int_rn(c * (100.0f * QSCALE));
                const unsigned rec = (q << 11) | (unsigned)(((xb & 63) << 5) | (yb & 31));
                const unsigned pos = atomicAdd(&sCur[tile], 1u);
                records[pos] = rec;
            }
        }
    }
}

// ---------- K4: dense-tile LDS accumulate, u64 packed fixed-point atomics ----------
// Record loads vectorized: uint4 (4 records/thread/iter), aligned base with
// head/tail predication -> 4x fewer VMEM insts, 4x decode ILP.
__global__ __launch_bounds__(K4_BS)
void accum_slot_kernel(const unsigned* __restrict__ records,
                       const unsigned* __restrict__ sums,
                       const unsigned* __restrict__ dstart,
                       const unsigned* __restrict__ vstart,
                       const float* __restrict__ palette,
                       float* __restrict__ slots)
{
    __shared__ unsigned long long img01[TPIX];   // ch0|ch1 packed, 16 KB
    __shared__ unsigned long long img23[TPIX];   // ch2|ch3 packed, 16 KB
    __shared__ float4 sPal[FID + 1];
    __shared__ unsigned tstart[NTILES + 1];
    __shared__ unsigned dst[NTILES + 1];
    __shared__ unsigned vst[NTILES];
    const int t = threadIdx.x;
    for (int i = t; i < NTILES + 1; i += K4_BS) { tstart[i] = sums[i]; dst[i] = dstart[i]; }
    for (int i = t; i < NTILES; i += K4_BS) vst[i] = vstart[i];
    for (int i = t; i < (FID + 1) * 4; i += K4_BS) ((float*)sPal)[i] = palette[i];
    __syncthreads();

    const unsigned dtotal = dst[NTILES];
    const unsigned r0 = (unsigned)blockIdx.x * CHUNK;
    if (r0 >= dtotal) return;
    const unsigned r1 = min(r0 + (unsigned)CHUNK, dtotal);

    int lo = 0, hi = NTILES;
    while (lo < hi) {
        const int mid = (lo + hi + 1) >> 1;
        if (dst[mid] <= r0) lo = mid; else hi = mid - 1;
    }

    for (int tile = lo; tile < NTILES && dst[tile] < r1; ++tile) {
        const unsigned sd = max(dst[tile], r0);
        const unsigned ed = min(dst[tile + 1], r1);
        if (sd >= ed) continue;
        const unsigned gs = tstart[tile] + (sd - dst[tile]);
        const unsigned ge = gs + (ed - sd);

        for (int i = t; i < TPIX; i += K4_BS) { img01[i] = 0ull; img23[i] = 0ull; }
        __syncthreads();

        // 2 u64 atomics per record. Fixed-point 2^17: CHUNK x 2^17 = 2^31 < 2^32 (u32).
        const unsigned abase = gs & ~3u;
        for (unsigned i = abase + 4u * (unsigned)t; i < ge; i += 4u * K4_BS) {
            const uint4 r4 = *(const uint4*)&records[i];
            const unsigned rr[4] = { r4.x, r4.y, r4.z, r4.w };
#pragma unroll
            for (int j = 0; j < 4; ++j) {
                const unsigned ri = i + (unsigned)j;
                if (ri >= gs && ri < ge) {
                    int pix; float v0, v1, v2, v3;
                    decode_rec(rr[j], sPal, pix, v0, v1, v2, v3);
                    atomicAdd(&img01[pix], pack2(v0, v1));
                    atomicAdd(&img23[pix], pack2(v2, v3));
                }
            }
        }
        __syncthreads();

        const unsigned slot = vst[tile] + ((unsigned)blockIdx.x - dst[tile] / CHUNK);
        float* sp = slots + (size_t)slot * (4 * TPIX);
        for (int i2 = t; i2 < TPIX; i2 += K4_BS) {
            const unsigned long long a = img01[i2];
            const unsigned long long bb = img23[i2];
            sp[0 * TPIX + i2] = (float)(unsigned)(a  & 0xFFFFFFFFu) * FXSI;
            sp[1 * TPIX + i2] = (float)(unsigned)(a  >> 32)         * FXSI;
            sp[2 * TPIX + i2] = (float)(unsigned)(bb & 0xFFFFFFFFu) * FXSI;
            sp[3 * TPIX + i2] = (float)(unsigned)(bb >> 32)         * FXSI;
        }
        __syncthreads();
    }
}

// ---------- K5: one 1024-thread block per tile: slots sum + single-pass sparse ----------
__global__ __launch_bounds__(1024)
void reduce_kernel(const float* __restrict__ slots,
                   const unsigned* __restrict__ vstart,
                   const unsigned* __restrict__ sums,
                   const unsigned* __restrict__ records,
                   const float* __restrict__ palette,
                   const float* __restrict__ raw0,
                   float* __restrict__ out)
{
    __shared__ unsigned long long l01[TPIX];     // 16 KB
    __shared__ unsigned long long l23[TPIX];     // 16 KB
    __shared__ float4 sPal[FID + 1];
    const int T = blockIdx.x;               // tile
    const int t = threadIdx.x;
    for (int i = t; i < (FID + 1) * 4; i += 1024) ((float*)sPal)[i] = palette[i];

    const unsigned v0 = vstart[T], v1 = vstart[T + 1];
    const unsigned s = sums[T], e = sums[T + 1];
    const bool sparse = (v0 == v1) && (e > s);
    if (sparse) for (int i = t; i < TPIX; i += 1024) { l01[i] = 0ull; l23[i] = 0ull; }
    __syncthreads();

    // slot partial sums: thread owns float4 indices t and t+1024 (of 2048/slot)
    float4 acc0 = {0.f,0.f,0.f,0.f}, acc1 = {0.f,0.f,0.f,0.f};
    for (unsigned v = v0; v < v1; ++v) {
        const float4* sp = (const float4*)(slots + (size_t)v * (4 * TPIX));
        const float4 a = sp[t];
        const float4 bq = sp[t + 1024];
        acc0.x += a.x;  acc0.y += a.y;  acc0.z += a.z;  acc0.w += a.w;
        acc1.x += bq.x; acc1.y += bq.y; acc1.z += bq.z; acc1.w += bq.w;
    }

    if (sparse) {
        // < TH records: 2^17 fixed-point safe ((TH-1) * 2^17 < 2^32 unsigned)
        for (unsigned i = s + t; i < e; i += 1024) {
            int pix; float w0, w1, w2, w3;
            decode_rec(records[i], sPal, pix, w0, w1, w2, w3);
            atomicAdd(&l01[pix], pack2(w0, w1));
            atomicAdd(&l23[pix], pack2(w2, w3));
        }
    }
    __syncthreads();

    const int tx = T >> 5, ty = T & 31;
#pragma unroll
    for (int half = 0; half < 2; ++half) {
        const int f  = t + half * 1024;     // float4 index in [0, 2048)
        const int ch = f >> 9;              // TPIX/4 = 512 float4s per channel
        const int q  = f & 511;
        const int p0 = q * 4;               // first of 4 consecutive local pixels
        float4 acc = half ? acc1 : acc0;
        if (sparse) {
#pragma unroll
            for (int j = 0; j < 4; ++j) {
                const int p = p0 + j;
                float vadd;
                if (ch == 0)      vadd = (float)(unsigned)(l01[p] & 0xFFFFFFFFu) * FXSI;
                else if (ch == 1) vadd = (float)(unsigned)(l01[p] >> 32) * FXSI;
                else if (ch == 2) vadd = (float)(unsigned)(l23[p] & 0xFFFFFFFFu) * FXSI;
                else              vadd = (float)(unsigned)(l23[p] >> 32) * FXSI;
                if (j == 0) acc.x += vadd;
                else if (j == 1) acc.y += vadd;
                else if (j == 2) acc.z += vadd;
                else acc.w += vadd;
            }
        }
        const int px = p0 >> 5, py = p0 & 31;
        const size_t o = (size_t)ch * HW + (size_t)(tx * 64 + px) * W + (ty * 32 + py);
        const float4 r = *(const float4*)(raw0 + o);
        acc.x += r.x; acc.y += r.y; acc.z += r.z; acc.w += r.w;
        *(float4*)(out + o) = acc;
    }
}

// ---------- Fallback: direct planar atomics ----------
__global__ __launch_bounds__(256)
void flame_kernel_planar(const float* __restrict__ points,
                         const int* __restrict__ choices,
                         const float* __restrict__ A,
                         const float* __restrict__ b,
                         const float* __restrict__ fc,
                         const float* __restrict__ palette,
                         const float* __restrict__ min_vec,
                         const float* __restrict__ range_vec,
                         const int* __restrict__ skipp,
                         float* __restrict__ out)
{
    __shared__ float sA[NF * 4];
    __shared__ float sB[NF * 2];
    __shared__ float sFC[NF];
    __shared__ float4 sPal[FID + 1];
    const int t = threadIdx.x;
    if (t < NF * 4) sA[t] = A[t];
    if (t < NF * 2) sB[t] = b[t];
    if (t < NF)     sFC[t] = fc[t];
    for (int i = t; i < (FID + 1) * 4; i += 256) ((float*)sPal)[i] = palette[i];
    __syncthreads();

    const int n = blockIdx.x * 256 + t;
    float x = points[3 * n], y = points[3 * n + 1], c = points[3 * n + 2];
    const float mx = min_vec[0], my = min_vec[1];
    const float rx = range_vec[0], ry = range_vec[1];
    const int skip = skipp[0];

    for (int k = 0; k < KSTEPS; ++k) {
        const int idx = choices[k * NPTS + n];
        const float nx = sA[idx*4+0]*x + sA[idx*4+1]*y + sB[idx*2+0];
        const float ny = sA[idx*4+2]*x + sA[idx*4+3]*y + sB[idx*2+1];
        c = 0.5f * (c + sFC[idx]);
        x = nx; y = ny;
        const float _c = c * (float)FID;
        const float cf = floorf(_c);
        const float tt = _c - cf;
        const int cfi = (int)fminf(fmaxf(cf, 0.f), (float)FID);
        const int cci = (int)fminf(fmaxf(ceilf(_c), 0.f), (float)FID);
        const float4 pc = sPal[cci];
        const float4 pf = sPal[cfi];
        const int xb = (int)((nx - mx) * rx);
        const int yb = (int)((ny - my) * ry);
        if (k >= skip && (unsigned)xb < (unsigned)W && (unsigned)yb < (unsigned)H) {
            const int p = xb * W + yb;
            const float omt = 1.f - tt;
            atomicAdd(out + p + 0 * HW, tt * pc.x + omt * pf.x);
            atomicAdd(out + p + 1 * HW, tt * pc.y + omt * pf.y);
            atomicAdd(out + p + 2 * HW, tt * pc.z + omt * pf.z);
            atomicAdd(out + p + 3 * HW, tt * pc.w + omt * pf.w);
        }
    }
}

extern "C" void kernel_launch(void* const* d_in, const int* in_sizes, int n_in,
                              void* d_out, int out_size, void* d_ws, size_t ws_size,
                              hipStream_t stream) {
    const float* points    = (const float*)d_in[0];
    const int*   choices   = (const int*)d_in[1];
    const float* A         = (const float*)d_in[2];
    const float* b         = (const float*)d_in[3];
    const float* fc        = (const float*)d_in[4];
    const float* palette   = (const float*)d_in[5];
    const float* min_vec   = (const float*)d_in[6];
    const float* range_vec = (const float*)d_in[7];
    const float* raw0      = (const float*)d_in[8];
    const int*   skipp     = (const int*)d_in[9];
    float* out = (float*)d_out;
    const size_t img_bytes = (size_t)4 * HW * sizeof(float);   // 16 MB

    // Layout: records | sums | dstart | vstart | slots-region.
    // packed (8 MB) and hist (8 MB) live INSIDE the slots region: both are
    // dead before K4 writes slots (stream-ordered), so no extra footprint.
    const size_t rec_off  = 0;
    const size_t rec_cap  = (size_t)MAXREC * 4;                 // 84 MB (u32 records)
    const size_t sums_off = rec_off + rec_cap;
    const size_t dst_off  = sums_off + 4096;
    const size_t vst_off  = dst_off + 4096;
    const size_t slot_off = vst_off + 4096;
    const size_t slot_cap = (size_t)MAXVIS * (4 * TPIX) * sizeof(float);  // 58.7 MB
    const size_t pk_off   = slot_off;                           // 8 MB
    const size_t hist_off = slot_off + (size_t)NPTS * 8;        // 8 MiB
    const size_t need1    = slot_off + slot_cap;                // ~143 MB

    unsigned* sums = (unsigned*)((char*)d_ws + sums_off);
    unsigned* recs = (unsigned*)((char*)d_ws + rec_off);

    if (ws_size >= need1) {
        unsigned* hist   = (unsigned*)((char*)d_ws + hist_off);
        unsigned* dstart = (unsigned*)((char*)d_ws + dst_off);
        unsigned* vstart = (unsigned*)((char*)d_ws + vst_off);
        float*    slots  = (float*)((char*)d_ws + slot_off);
        unsigned long long* packed = (unsigned long long*)((char*)d_ws + pk_off);

        count_kernel<<<NBLK_C, 256, 0, stream>>>(
            points, choices, A, b, min_vec, range_vec, skipp, hist, packed);
        scan1_kernel<<<NTILES, 1024, 0, stream>>>(hist, sums);
        scan2v_kernel<<<1, 512, 0, stream>>>(sums, dstart, vstart);
        scatter_kernel<<<NBLK, 256, 0, stream>>>(
            points, packed, A, b, fc, min_vec, range_vec, skipp, hist, sums, recs);
        accum_slot_kernel<<<K4_GRID, K4_BS, 0, stream>>>(
            recs, sums, dstart, vstart, palette, slots);
        reduce_kernel<<<NTILES, 1024, 0, stream>>>(
            slots, vstart, sums, recs, palette, raw0, out);
    } else {
        hipMemcpyAsync(out, raw0, img_bytes, hipMemcpyDeviceToDevice, stream);
        flame_kernel_planar<<<NPTS / 256, 256, 0, stream>>>(
            points, choices, A, b, fc, palette, min_vec, range_vec, skipp, out);
    }
}